// Round 15
// baseline (150.283 us; speedup 1.0000x reference)
//
#include <hip/hip_runtime.h>
#include <hip/hip_bf16.h>
#include <math.h>

typedef __attribute__((ext_vector_type(4))) float f32x4;
typedef __attribute__((ext_vector_type(16))) float f32x16;
typedef __attribute__((ext_vector_type(8))) short bf16x8;
typedef __attribute__((ext_vector_type(4))) short s16x4;
typedef __attribute__((ext_vector_type(4))) unsigned int u32x4;
typedef __attribute__((ext_vector_type(2))) unsigned int u32x2;
typedef short s16;
typedef unsigned int u32;
typedef unsigned short u16;
typedef unsigned long long u64;

#define S_LEN 2048
#define HIDN  2048
#define QKVW  3072
#define NH    32
#define NKVH  8
#define HD    64

__device__ __forceinline__ s16 f2bf(float f) {
  unsigned int u = __float_as_uint(f);
  unsigned int lsb = (u >> 16) & 1u;
  u += 0x7fffu + lsb;
  return (s16)(u >> 16);
}

__device__ __forceinline__ u32 cvtpk(float lo, float hi) {
  u32 r;
  asm("v_cvt_pk_bf16_f32 %0, %1, %2" : "=v"(r) : "v"(lo), "v"(hi));
  return r;
}

__device__ __forceinline__ void gload16(const void* g, void* l) {
  __builtin_amdgcn_global_load_lds(
      (const __attribute__((address_space(1))) void*)g,
      (__attribute__((address_space(3))) void*)l, 16, 0, 0);
}

// v_permlane32_swap_b32: a.hi-lanes <-> b.lo-lanes
__device__ __forceinline__ void pls(u32& a, u32& b) {
  asm volatile("v_permlane32_swap_b32 %0, %1" : "+v"(a), "+v"(b));
}

__device__ __forceinline__ int swz7(int row) { return (row ^ (row >> 3)) & 7; }

// all 5 f32->bf16 conversions in one launch; dest regions are contiguous in ws
__global__ __launch_bounds__(256) void cvt_all(const float* __restrict__ h,
                                               const float* __restrict__ wq,
                                               const float* __restrict__ wk,
                                               const float* __restrict__ wv,
                                               const float* __restrict__ wo,
                                               s16x4* __restrict__ dst) {
  int i = blockIdx.x * 256 + threadIdx.x;
  const float* src; int off;
  if (i < 1048576)      { src = h;  off = i; }
  else if (i < 2097152) { src = wq; off = i - 1048576; }
  else if (i < 2359296) { src = wk; off = i - 2097152; }
  else if (i < 2621440) { src = wv; off = i - 2359296; }
  else                  { src = wo; off = i - 2621440; }
  if (i < 3670016) {
    float4 f = reinterpret_cast<const float4*>(src)[off];
    s16x4 o;
    o.x = f2bf(f.x); o.y = f2bf(f.y); o.z = f2bf(f.z); o.w = f2bf(f.w);
    dst[i] = o;
  }
}

__device__ __forceinline__ void storeC(s16* C, size_t idx, float v)   { C[idx] = f2bf(v); }
__device__ __forceinline__ void storeC(float* C, size_t idx, float v) { C[idx] = v; }

// C[M,N] = A[M,K] * B[N,K]^T. BM=BN=128, BK=64, 512 threads (8 waves 2x4),
// double-buffered LDS, 2-phase schedule, swz7 slot swizzle, XCD block swizzle.
template <typename OUT_T>
__global__ __launch_bounds__(512) void gemm_bt(const s16* __restrict__ A,
                                               const s16* __restrict__ B,
                                               OUT_T* __restrict__ C,
                                               int M, int N, int K, int gridX) {
  __shared__ alignas(16) s16 As[2][8192];   // [128][64], 16KB each
  __shared__ alignas(16) s16 Bs[2][8192];

  // bijective XCD swizzle (m204): each XCD gets a contiguous tile range
  const int nwg  = (M >> 7) * gridX;
  const int flat = blockIdx.x;
  const int q8   = nwg >> 3;
  const int swz  = (flat & 7) * q8 + (flat >> 3);
  const int bm   = (swz / gridX) * 128;
  const int bn   = (swz % gridX) * 128;

  const int t    = threadIdx.x;
  const int lane = t & 63;
  const int w    = t >> 6;            // 0..7
  const int wr   = (w >> 2) * 64;     // wave-tile 64x32
  const int wc   = (w & 3) * 32;
  const int lr   = lane & 15;
  const int lg   = lane >> 4;

  // staging: 16 chunks of 1KB per matrix; wave w does chunks {2w, 2w+1}
  const int srow0 = (w * 2) * 8 + (lane >> 3);
  const int srow1 = (w * 2 + 1) * 8 + (lane >> 3);
  const int sl0   = ((lane & 7) ^ swz7(srow0)) * 8;
  const int sl1   = ((lane & 7) ^ swz7(srow1)) * 8;

  f32x4 acc[4][2];
#pragma unroll
  for (int m = 0; m < 4; ++m)
#pragma unroll
    for (int n = 0; n < 2; ++n)
      acc[m][n] = (f32x4){0.f, 0.f, 0.f, 0.f};

  const int nK = K >> 6;
  int buf = 0;

  // prologue: stage tile 0
  {
    gload16(&A[(size_t)(bm + srow0) * K + sl0], (char*)As[0] + (w * 2) * 1024);
    gload16(&A[(size_t)(bm + srow1) * K + sl1], (char*)As[0] + (w * 2 + 1) * 1024);
    gload16(&B[(size_t)(bn + srow0) * K + sl0], (char*)Bs[0] + (w * 2) * 1024);
    gload16(&B[(size_t)(bn + srow1) * K + sl1], (char*)Bs[0] + (w * 2 + 1) * 1024);
  }
  __syncthreads();

  for (int ki = 0; ki < nK; ++ki) {
    if (ki + 1 < nK) {
      const int kt = (ki + 1) << 6;
      gload16(&A[(size_t)(bm + srow0) * K + kt + sl0], (char*)As[buf ^ 1] + (w * 2) * 1024);
      gload16(&A[(size_t)(bm + srow1) * K + kt + sl1], (char*)As[buf ^ 1] + (w * 2 + 1) * 1024);
      gload16(&B[(size_t)(bn + srow0) * K + kt + sl0], (char*)Bs[buf ^ 1] + (w * 2) * 1024);
      gload16(&B[(size_t)(bn + srow1) * K + kt + sl1], (char*)Bs[buf ^ 1] + (w * 2 + 1) * 1024);
    }

    bf16x8 af[4][2], bfr[2][2];
#pragma unroll
    for (int kk = 0; kk < 2; ++kk) {
#pragma unroll
      for (int m = 0; m < 4; ++m) {
        int row = wr + m * 16 + lr;
        af[m][kk] = *(bf16x8*)((char*)As[buf] + row * 128 + (((kk * 4 + lg) ^ swz7(row)) << 4));
      }
#pragma unroll
      for (int n = 0; n < 2; ++n) {
        int row = wc + n * 16 + lr;
        bfr[n][kk] = *(bf16x8*)((char*)Bs[buf] + row * 128 + (((kk * 4 + lg) ^ swz7(row)) << 4));
      }
    }

    __builtin_amdgcn_s_setprio(1);
#pragma unroll
    for (int m = 0; m < 4; ++m)
#pragma unroll
      for (int n = 0; n < 2; ++n)
#pragma unroll
        for (int kk = 0; kk < 2; ++kk)
          acc[m][n] = __builtin_amdgcn_mfma_f32_16x16x32_bf16(af[m][kk], bfr[n][kk], acc[m][n], 0, 0, 0);
    __builtin_amdgcn_s_setprio(0);

    __syncthreads();
    buf ^= 1;
  }

#pragma unroll
  for (int m = 0; m < 4; ++m)
#pragma unroll
    for (int n = 0; n < 2; ++n) {
      int row = bm + wr + m * 16 + lg * 4;
      int col = bn + wc + n * 16 + lr;
#pragma unroll
      for (int j = 0; j < 4; ++j)
        storeC(C, (size_t)(row + j) * N + col, acc[m][n][j]);
    }
}

// ---------------- flash attention: split-KV 8-wave, KVBLK=128/group ----------
// Block = (hk, p): phase 0 runs q-tile 63-p, phase 1 runs q-tile p (uniform
// 9 rounds/block total). 512 threads = 2 KV-split groups x 4 heads; group g
// owns 64-kv subtile pairs {4i+2g, 4i+2g+1} per round with private
// double-buffered K/V LDS (2x2x32KB); in-LDS 2-way merge per phase.
__global__ __launch_bounds__(512) void attn_kernel(
    const s16* __restrict__ QKV,   // [2048][3072]
    const int* __restrict__ am,    // [2048]
    s16* __restrict__ Ob) {        // [2048][2048]
  // group g at +g*65536; buf b at +b*32768; K0 +0, V0 +8192, K1 +16384, V1 +24576
  __shared__ alignas(16) char smem[131072];
  __shared__ float2 mlb[4][64];

  const int t    = threadIdx.x;
  const int g    = t >> 8;        // kv-split group
  const int tg   = t & 255;       // tid within group
  const int lane = t & 63;
  const int w    = tg >> 6;       // head index within group
  const int col  = lane & 31;     // q column (this wave's q-row index)
  const int hi   = lane >> 5;

  const int hk = blockIdx.x;
  const int p  = blockIdx.y;      // 0..31
  const int h  = hk * 4 + w;
  const int kbase = 2048 + hk * 64;
  const int vbase = 2560 + hk * 64;
  const float CF = 0.18033688f;  // 0.125 * log2(e)

  const int krow   = lane >> 3;
  const int kslotb = lane & 7;
  const int vkv    = 2 * (tg >> 3);
  const int vd8    = (tg & 7) * 8;

  char* gbase = smem + g * 65536;

  for (int phase = 0; phase < 2; ++phase) {
    const int qt = phase ? p : 63 - p;
    const int nt = (qt >> 1) + 1;     // # 64-kv tiles
    const int R  = (nt + 3) >> 2;     // rounds (4 tiles/round across 2 groups)
    const int qrow = qt * 32 + col;

    bf16x8 qf[4];
#pragma unroll
    for (int ds = 0; ds < 4; ++ds)
      qf[ds] = *(const bf16x8*)&QKV[(size_t)qrow * QKVW + h * 64 + ds * 16 + hi * 8];

    // ---- prologue: stage tiles 2g, 2g+1 into buf 0 (indices in-bounds) ----
    {
#pragma unroll
      for (int sub = 0; sub < 2; ++sub) {
        const int tt = 2 * g + sub;
        char* Kd = gbase + sub * 16384;
        char* Vd = Kd + 8192;
#pragma unroll
        for (int pp = 0; pp < 2; ++pp) {
          int c   = w * 2 + pp;
          int row = c * 8 + krow;
          int slot = kslotb ^ swz7(row);
          gload16(&QKV[(size_t)(tt * 64 + row) * QKVW + kbase + slot * 8], Kd + c * 1024);
        }
        bf16x8 va = *(const bf16x8*)&QKV[(size_t)(tt * 64 + vkv) * QKVW + vbase + vd8];
        bf16x8 vb = *(const bf16x8*)&QKV[(size_t)(tt * 64 + vkv + 1) * QKVW + vbase + vd8];
#pragma unroll
        for (int i = 0; i < 8; ++i) {
          int d = vd8 + i;
          u32 pk = (u32)(u16)va[i] | ((u32)(u16)vb[i] << 16);
          *(u32*)&Vd[(d * 128 + vkv * 2) ^ (swz7(d) << 4)] = pk;
        }
      }
    }
    int a0 = am[2 * g * 64 + lane];
    int a1 = am[2 * g * 64 + 64 + lane];

    float m_i = -1e30f, l_part = 0.f;
    f32x16 Oacc[2];
#pragma unroll
    for (int b = 0; b < 2; ++b)
#pragma unroll
      for (int i = 0; i < 16; ++i) Oacc[b][i] = 0.f;
    __syncthreads();

    for (int it = 0; it < R; ++it) {
      const int buf = it & 1;
      const int t0  = 4 * it + 2 * g;
      const int kv0 = t0 * 64;
      const bool v0 = (t0 < nt);
      const bool v1 = (t0 + 1 < nt);

      char* Kc0 = gbase + buf * 32768;
      char* Vc0 = Kc0 + 8192;
      char* Kc1 = Kc0 + 16384;
      char* Vc1 = Kc0 + 24576;
      char* Kn  = gbase + (buf ^ 1) * 32768;

      // ---- prefetch next round's two subtiles (issue early) ----
      bf16x8 va0, vb0, va1, vb1;
      int an0 = 0, an1 = 0;
      const bool p0 = (t0 + 4 < nt), p1 = (t0 + 5 < nt);
      if (p0) {
        const int nk = kv0 + 256;
#pragma unroll
        for (int pp = 0; pp < 2; ++pp) {
          int c   = w * 2 + pp;
          int row = c * 8 + krow;
          int slot = kslotb ^ swz7(row);
          gload16(&QKV[(size_t)(nk + row) * QKVW + kbase + slot * 8], Kn + c * 1024);
        }
        va0 = *(const bf16x8*)&QKV[(size_t)(nk + vkv) * QKVW + vbase + vd8];
        vb0 = *(const bf16x8*)&QKV[(size_t)(nk + vkv + 1) * QKVW + vbase + vd8];
        an0 = am[nk + lane];
      }
      if (p1) {
        const int nk = kv0 + 320;
#pragma unroll
        for (int pp = 0; pp < 2; ++pp) {
          int c   = w * 2 + pp;
          int row = c * 8 + krow;
          int slot = kslotb ^ swz7(row);
          gload16(&QKV[(size_t)(nk + row) * QKVW + kbase + slot * 8], Kn + 16384 + c * 1024);
        }
        va1 = *(const bf16x8*)&QKV[(size_t)(nk + vkv) * QKVW + vbase + vd8];
        vb1 = *(const bf16x8*)&QKV[(size_t)(nk + vkv + 1) * QKVW + vbase + vd8];
        an1 = am[nk + lane];
      }

      // ---- sub0: S^T = K Q^T then mask -> pvA ----
      float pvA[32], pvB[32];
      {
        f32x16 s0, s1;
#pragma unroll
        for (int i = 0; i < 16; ++i) { s0[i] = 0.f; s1[i] = 0.f; }
        __builtin_amdgcn_s_setprio(1);
#pragma unroll
        for (int ds = 0; ds < 4; ++ds) {
          int off = ds * 32 + hi * 16;
          bf16x8 k0 = *(bf16x8*)&Kc0[(col * 128 + off) ^ (swz7(col) << 4)];
          bf16x8 k1 = *(bf16x8*)&Kc0[((32 + col) * 128 + off) ^ (swz7(32 + col) << 4)];
          s0 = __builtin_amdgcn_mfma_f32_32x32x16_bf16(k0, qf[ds], s0, 0, 0, 0);
          s1 = __builtin_amdgcn_mfma_f32_32x32x16_bf16(k1, qf[ds], s1, 0, 0, 0);
        }
        __builtin_amdgcn_s_setprio(0);
        u64 m64 = __ballot(a0 != 0);
        bool inter = v0 && (kv0 + 64 <= qt * 32) && (m64 == ~0ull);
        if (inter) {
#pragma unroll
          for (int r = 0; r < 16; ++r) { pvA[r] = s0[r]; pvA[16 + r] = s1[r]; }
        } else {
#pragma unroll
          for (int b = 0; b < 2; ++b)
#pragma unroll
            for (int r = 0; r < 16; ++r) {
              int kvl = b * 32 + (r & 3) + 8 * (r >> 2) + 4 * hi;
              float sv = b ? s1[r] : s0[r];
              bool ok = v0 && (kv0 + kvl <= qrow) && ((m64 >> kvl) & 1ull);
              pvA[b * 16 + r] = ok ? sv : -INFINITY;
            }
        }
      }
      // ---- sub1 -> pvB ----
      {
        f32x16 s0, s1;
#pragma unroll
        for (int i = 0; i < 16; ++i) { s0[i] = 0.f; s1[i] = 0.f; }
        __builtin_amdgcn_s_setprio(1);
#pragma unroll
        for (int ds = 0; ds < 4; ++ds) {
          int off = ds * 32 + hi * 16;
          bf16x8 k0 = *(bf16x8*)&Kc1[(col * 128 + off) ^ (swz7(col) << 4)];
          bf16x8 k1 = *(bf16x8*)&Kc1[((32 + col) * 128 + off) ^ (swz7(32 + col) << 4)];
          s0 = __builtin_amdgcn_mfma_f32_32x32x16_bf16(k0, qf[ds], s0, 0, 0, 0);
          s1 = __builtin_amdgcn_mfma_f32_32x32x16_bf16(k1, qf[ds], s1, 0, 0, 0);
        }
        __builtin_amdgcn_s_setprio(0);
        u64 m64 = __ballot(a1 != 0);
        const int kvb = kv0 + 64;
        bool inter = v1 && (kvb + 64 <= qt * 32) && (m64 == ~0ull);
        if (inter) {
#pragma unroll
          for (int r = 0; r < 16; ++r) { pvB[r] = s0[r]; pvB[16 + r] = s1[r]; }
        } else {
#pragma unroll
          for (int b = 0; b < 2; ++b)
#pragma unroll
            for (int r = 0; r < 16; ++r) {
              int kvl = b * 32 + (r & 3) + 8 * (r >> 2) + 4 * hi;
              float sv = b ? s1[r] : s0[r];
              bool ok = v1 && (kvb + kvl <= qrow) && ((m64 >> kvl) & 1ull);
              pvB[b * 16 + r] = ok ? sv : -INFINITY;
            }
        }
      }

      // ---- joint online softmax over 128 kv (4-way trees + 1 shfl) ----
      float a0t = fmaxf(pvA[0], pvB[0]), a1t = fmaxf(pvA[1], pvB[1]);
      float a2t = fmaxf(pvA[2], pvB[2]), a3t = fmaxf(pvA[3], pvB[3]);
#pragma unroll
      for (int i = 4; i < 32; i += 4) {
        a0t = fmaxf(a0t, fmaxf(pvA[i],     pvB[i]));
        a1t = fmaxf(a1t, fmaxf(pvA[i + 1], pvB[i + 1]));
        a2t = fmaxf(a2t, fmaxf(pvA[i + 2], pvB[i + 2]));
        a3t = fmaxf(a3t, fmaxf(pvA[i + 3], pvB[i + 3]));
      }
      float lmax = fmaxf(fmaxf(a0t, a1t), fmaxf(a2t, a3t));
      lmax = fmaxf(lmax, __shfl_xor(lmax, 32));
      float lmaxs = lmax * CF;

      if (!__all(lmaxs - m_i <= 8.f)) {   // defer-max (T13)
        float nm = fmaxf(m_i, lmaxs);
        float al = __builtin_amdgcn_exp2f(m_i - nm);
        m_i = nm;
        l_part *= al;
#pragma unroll
        for (int b = 0; b < 2; ++b)
#pragma unroll
          for (int i = 0; i < 16; ++i) Oacc[b][i] *= al;
      }

      float s0t = 0.f, s1t = 0.f, s2t = 0.f, s3t = 0.f;
#pragma unroll
      for (int i = 0; i < 32; i += 4) {
        pvA[i]     = __builtin_amdgcn_exp2f(__builtin_fmaf(pvA[i],     CF, -m_i)); s0t += pvA[i];
        pvA[i + 1] = __builtin_amdgcn_exp2f(__builtin_fmaf(pvA[i + 1], CF, -m_i)); s1t += pvA[i + 1];
        pvA[i + 2] = __builtin_amdgcn_exp2f(__builtin_fmaf(pvA[i + 2], CF, -m_i)); s2t += pvA[i + 2];
        pvA[i + 3] = __builtin_amdgcn_exp2f(__builtin_fmaf(pvA[i + 3], CF, -m_i)); s3t += pvA[i + 3];
      }
#pragma unroll
      for (int i = 0; i < 32; i += 4) {
        pvB[i]     = __builtin_amdgcn_exp2f(__builtin_fmaf(pvB[i],     CF, -m_i)); s0t += pvB[i];
        pvB[i + 1] = __builtin_amdgcn_exp2f(__builtin_fmaf(pvB[i + 1], CF, -m_i)); s1t += pvB[i + 1];
        pvB[i + 2] = __builtin_amdgcn_exp2f(__builtin_fmaf(pvB[i + 2], CF, -m_i)); s2t += pvB[i + 2];
        pvB[i + 3] = __builtin_amdgcn_exp2f(__builtin_fmaf(pvB[i + 3], CF, -m_i)); s3t += pvB[i + 3];
      }
      l_part += (s0t + s1t) + (s2t + s3t);

      // ---- P -> PV B-fragments in-register (cvt_pk + permlane32_swap) ----
      bf16x8 pfA[4], pfB[4];
#pragma unroll
      for (int b = 0; b < 2; ++b)
#pragma unroll
        for (int gg = 0; gg < 2; ++gg) {
          int base = b * 16 + gg * 8;
          u32 A1 = cvtpk(pvA[base + 0], pvA[base + 1]);
          u32 A2 = cvtpk(pvA[base + 2], pvA[base + 3]);
          u32 B1 = cvtpk(pvA[base + 4], pvA[base + 5]);
          u32 B2 = cvtpk(pvA[base + 6], pvA[base + 7]);
          pls(A1, B1); pls(A2, B2);
          u32x4 pw; pw[0] = A1; pw[1] = A2; pw[2] = B1; pw[3] = B2;
          pfA[b * 2 + gg] = *reinterpret_cast<bf16x8*>(&pw);
          u32 C1 = cvtpk(pvB[base + 0], pvB[base + 1]);
          u32 C2 = cvtpk(pvB[base + 2], pvB[base + 3]);
          u32 D1 = cvtpk(pvB[base + 4], pvB[base + 5]);
          u32 D2 = cvtpk(pvB[base + 6], pvB[base + 7]);
          pls(C1, D1); pls(C2, D2);
          u32x4 qw; qw[0] = C1; qw[1] = C2; qw[2] = D1; qw[3] = D2;
          pfB[b * 2 + gg] = *reinterpret_cast<bf16x8*>(&qw);
        }

      // ---- O^T += V0^T P0^T + V1^T P1^T ----
      __builtin_amdgcn_s_setprio(1);
#pragma unroll
      for (int ks = 0; ks < 4; ++ks) {
        int off = ks * 32 + hi * 16;
#pragma unroll
        for (int db = 0; db < 2; ++db) {
          int d = db * 32 + col;
          int sw = swz7(d) << 4;
          bf16x8 vfA = *(bf16x8*)&Vc0[(d * 128 + off) ^ sw];
          Oacc[db] = __builtin_amdgcn_mfma_f32_32x32x16_bf16(vfA, pfA[ks], Oacc[db], 0, 0, 0);
          bf16x8 vfB = *(bf16x8*)&Vc1[(d * 128 + off) ^ sw];
          Oacc[db] = __builtin_amdgcn_mfma_f32_32x32x16_bf16(vfB, pfB[ks], Oacc[db], 0, 0, 0);
        }
      }
      __builtin_amdgcn_s_setprio(0);

      // ---- late half of async stage: pack + write V^T(next) ----
      if (p0) {
        char* Vn = Kn + 8192;
#pragma unroll
        for (int i = 0; i < 8; ++i) {
          int d = vd8 + i;
          u32 pk = (u32)(u16)va0[i] | ((u32)(u16)vb0[i] << 16);
          *(u32*)&Vn[(d * 128 + vkv * 2) ^ (swz7(d) << 4)] = pk;
        }
        a0 = an0;
      }
      if (p1) {
        char* Vn = Kn + 24576;
#pragma unroll
        for (int i = 0; i < 8; ++i) {
          int d = vd8 + i;
          u32 pk = (u32)(u16)va1[i] | ((u32)(u16)vb1[i] << 16);
          *(u32*)&Vn[(d * 128 + vkv * 2) ^ (swz7(d) << 4)] = pk;
        }
        a1 = an1;
      }
      __syncthreads();
    }

    // ---- merge the two groups' partials (in LDS), g1 stores final O ----
    float l_p = l_part + __shfl_xor(l_part, 32);

    if (g == 0) {
      // overlays only group 0's own staging area (first 64KB)
      float* pool = (float*)smem + w * 2048 + lane * 32;
#pragma unroll
      for (int b = 0; b < 2; ++b)
#pragma unroll
        for (int i = 0; i < 16; ++i) pool[b * 16 + i] = Oacc[b][i];
      mlb[w][lane] = make_float2(m_i, l_p);
    }
    __syncthreads();
    if (g == 1) {
      const float* pool = (const float*)smem + w * 2048 + lane * 32;
      float2 ml0 = mlb[w][lane];
      float mm = fmaxf(ml0.x, m_i);
      float b0 = __builtin_amdgcn_exp2f(ml0.x - mm);
      float b1 = __builtin_amdgcn_exp2f(m_i - mm);
      float linv = 1.0f / (ml0.y * b0 + l_p * b1);
      float sc0 = b0 * linv, sc1 = b1 * linv;
#pragma unroll
      for (int db = 0; db < 2; ++db)
#pragma unroll
        for (int qd = 0; qd < 4; ++qd) {
          float o0 = pool[db * 16 + qd * 4 + 0] * sc0 + Oacc[db][qd * 4 + 0] * sc1;
          float o1 = pool[db * 16 + qd * 4 + 1] * sc0 + Oacc[db][qd * 4 + 1] * sc1;
          float o2 = pool[db * 16 + qd * 4 + 2] * sc0 + Oacc[db][qd * 4 + 2] * sc1;
          float o3 = pool[db * 16 + qd * 4 + 3] * sc0 + Oacc[db][qd * 4 + 3] * sc1;
          u32x2 o;
          o[0] = cvtpk(o0, o1);
          o[1] = cvtpk(o2, o3);
          int d0 = db * 32 + qd * 8 + hi * 4;
          *(u32x2*)&Ob[(size_t)qrow * HIDN + h * 64 + d0] = o;
        }
    }
    __syncthreads();  // pool/mlb consumed before next phase's staging
  }
}

extern "C" void kernel_launch(void* const* d_in, const int* in_sizes, int n_in,
                              void* d_out, int out_size, void* d_ws, size_t ws_size,
                              hipStream_t stream) {
  const float* hidden = (const float*)d_in[0];
  const int*   am     = (const int*)d_in[1];
  const float* Wq     = (const float*)d_in[2];
  const float* Wk     = (const float*)d_in[3];
  const float* Wv     = (const float*)d_in[4];
  const float* Wo     = (const float*)d_in[5];
  float* out = (float*)d_out;

  s16* hb    = (s16*)d_ws;          // hidden  [2048][2048]
  s16* wqkvb = hb    + 4194304;     // W_qkv   [3072][2048]
  s16* wob   = wqkvb + 6291456;     // Wo      [2048][2048]
  s16* QKVb  = wob   + 4194304;     // QKV     [2048][3072]
  s16* Ab    = QKVb  + 6291456;     // attnout [2048][2048]

  cvt_all<<<14336, 256, 0, stream>>>(hidden, Wq, Wk, Wv, Wo, (s16x4*)d_ws);

  gemm_bt<s16><<<384, 512, 0, stream>>>(hb, wqkvb, QKVb, 2048, 3072, 2048, 24);

  attn_kernel<<<dim3(8, 32), 512, 0, stream>>>(QKVb, am, Ab);

  gemm_bt<float><<<256, 512, 0, stream>>>(Ab, wob, out, 2048, 2048, 2048, 16);
}

// Round 16
// 131.131 us; speedup vs baseline: 1.1460x; 1.1460x over previous
//
#include <hip/hip_runtime.h>
#include <hip/hip_bf16.h>
#include <math.h>

typedef __attribute__((ext_vector_type(4))) float f32x4;
typedef __attribute__((ext_vector_type(16))) float f32x16;
typedef __attribute__((ext_vector_type(8))) short bf16x8;
typedef __attribute__((ext_vector_type(4))) short s16x4;
typedef __attribute__((ext_vector_type(4))) unsigned int u32x4;
typedef __attribute__((ext_vector_type(2))) unsigned int u32x2;
typedef short s16;
typedef unsigned int u32;
typedef unsigned short u16;

#define S_LEN 2048
#define HIDN  2048
#define QKVW  3072
#define NH    32
#define NKVH  8
#define HD    64

__device__ __forceinline__ s16 f2bf(float f) {
  unsigned int u = __float_as_uint(f);
  unsigned int lsb = (u >> 16) & 1u;
  u += 0x7fffu + lsb;
  return (s16)(u >> 16);
}

__device__ __forceinline__ u32 cvtpk(float lo, float hi) {
  u32 r;
  asm("v_cvt_pk_bf16_f32 %0, %1, %2" : "=v"(r) : "v"(lo), "v"(hi));
  return r;
}

__device__ __forceinline__ void gload16(const void* g, void* l) {
  __builtin_amdgcn_global_load_lds(
      (const __attribute__((address_space(1))) void*)g,
      (__attribute__((address_space(3))) void*)l, 16, 0, 0);
}

// v_permlane32_swap_b32: a.hi-lanes <-> b.lo-lanes
__device__ __forceinline__ void pls(u32& a, u32& b) {
  asm volatile("v_permlane32_swap_b32 %0, %1" : "+v"(a), "+v"(b));
}

__device__ __forceinline__ int swz7(int row) { return (row ^ (row >> 3)) & 7; }

// all 5 f32->bf16 conversions in one launch; dest regions are contiguous in ws
__global__ __launch_bounds__(256) void cvt_all(const float* __restrict__ h,
                                               const float* __restrict__ wq,
                                               const float* __restrict__ wk,
                                               const float* __restrict__ wv,
                                               const float* __restrict__ wo,
                                               s16x4* __restrict__ dst) {
  int i = blockIdx.x * 256 + threadIdx.x;
  const float* src; int off;
  if (i < 1048576)      { src = h;  off = i; }
  else if (i < 2097152) { src = wq; off = i - 1048576; }
  else if (i < 2359296) { src = wk; off = i - 2097152; }
  else if (i < 2621440) { src = wv; off = i - 2359296; }
  else                  { src = wo; off = i - 2621440; }
  if (i < 3670016) {
    float4 f = reinterpret_cast<const float4*>(src)[off];
    s16x4 o;
    o.x = f2bf(f.x); o.y = f2bf(f.y); o.z = f2bf(f.z); o.w = f2bf(f.w);
    dst[i] = o;
  }
}

__device__ __forceinline__ void storeC(s16* C, size_t idx, float v)   { C[idx] = f2bf(v); }
__device__ __forceinline__ void storeC(float* C, size_t idx, float v) { C[idx] = v; }

// C[M,N] = A[M,K] * B[N,K]^T. BM=BN=128, BK=64, 512 threads (8 waves 2x4),
// double-buffered LDS, 2-phase schedule, swz7 slot swizzle, XCD block swizzle.
template <typename OUT_T>
__global__ __launch_bounds__(512) void gemm_bt(const s16* __restrict__ A,
                                               const s16* __restrict__ B,
                                               OUT_T* __restrict__ C,
                                               int M, int N, int K, int gridX) {
  __shared__ alignas(16) s16 As[2][8192];   // [128][64], 16KB each
  __shared__ alignas(16) s16 Bs[2][8192];

  // bijective XCD swizzle (m204): each XCD gets a contiguous tile range
  const int nwg  = (M >> 7) * gridX;
  const int flat = blockIdx.x;
  const int q8   = nwg >> 3;
  const int swz  = (flat & 7) * q8 + (flat >> 3);
  const int bm   = (swz / gridX) * 128;
  const int bn   = (swz % gridX) * 128;

  const int t    = threadIdx.x;
  const int lane = t & 63;
  const int w    = t >> 6;            // 0..7
  const int wr   = (w >> 2) * 64;     // wave-tile 64x32
  const int wc   = (w & 3) * 32;
  const int lr   = lane & 15;
  const int lg   = lane >> 4;

  // staging: 16 chunks of 1KB per matrix; wave w does chunks {2w, 2w+1}
  const int srow0 = (w * 2) * 8 + (lane >> 3);
  const int srow1 = (w * 2 + 1) * 8 + (lane >> 3);
  const int sl0   = ((lane & 7) ^ swz7(srow0)) * 8;
  const int sl1   = ((lane & 7) ^ swz7(srow1)) * 8;

  f32x4 acc[4][2];
#pragma unroll
  for (int m = 0; m < 4; ++m)
#pragma unroll
    for (int n = 0; n < 2; ++n)
      acc[m][n] = (f32x4){0.f, 0.f, 0.f, 0.f};

  const int nK = K >> 6;
  int buf = 0;

  // prologue: stage tile 0
  {
    gload16(&A[(size_t)(bm + srow0) * K + sl0], (char*)As[0] + (w * 2) * 1024);
    gload16(&A[(size_t)(bm + srow1) * K + sl1], (char*)As[0] + (w * 2 + 1) * 1024);
    gload16(&B[(size_t)(bn + srow0) * K + sl0], (char*)Bs[0] + (w * 2) * 1024);
    gload16(&B[(size_t)(bn + srow1) * K + sl1], (char*)Bs[0] + (w * 2 + 1) * 1024);
  }
  __syncthreads();

  for (int ki = 0; ki < nK; ++ki) {
    if (ki + 1 < nK) {
      const int kt = (ki + 1) << 6;
      gload16(&A[(size_t)(bm + srow0) * K + kt + sl0], (char*)As[buf ^ 1] + (w * 2) * 1024);
      gload16(&A[(size_t)(bm + srow1) * K + kt + sl1], (char*)As[buf ^ 1] + (w * 2 + 1) * 1024);
      gload16(&B[(size_t)(bn + srow0) * K + kt + sl0], (char*)Bs[buf ^ 1] + (w * 2) * 1024);
      gload16(&B[(size_t)(bn + srow1) * K + kt + sl1], (char*)Bs[buf ^ 1] + (w * 2 + 1) * 1024);
    }

    bf16x8 af[4][2], bfr[2][2];
#pragma unroll
    for (int kk = 0; kk < 2; ++kk) {
#pragma unroll
      for (int m = 0; m < 4; ++m) {
        int row = wr + m * 16 + lr;
        af[m][kk] = *(bf16x8*)((char*)As[buf] + row * 128 + (((kk * 4 + lg) ^ swz7(row)) << 4));
      }
#pragma unroll
      for (int n = 0; n < 2; ++n) {
        int row = wc + n * 16 + lr;
        bfr[n][kk] = *(bf16x8*)((char*)Bs[buf] + row * 128 + (((kk * 4 + lg) ^ swz7(row)) << 4));
      }
    }

    __builtin_amdgcn_s_setprio(1);
#pragma unroll
    for (int m = 0; m < 4; ++m)
#pragma unroll
      for (int n = 0; n < 2; ++n)
#pragma unroll
        for (int kk = 0; kk < 2; ++kk)
          acc[m][n] = __builtin_amdgcn_mfma_f32_16x16x32_bf16(af[m][kk], bfr[n][kk], acc[m][n], 0, 0, 0);
    __builtin_amdgcn_s_setprio(0);

    __syncthreads();
    buf ^= 1;
  }

#pragma unroll
  for (int m = 0; m < 4; ++m)
#pragma unroll
    for (int n = 0; n < 2; ++n) {
      int row = bm + wr + m * 16 + lg * 4;
      int col = bn + wc + n * 16 + lr;
#pragma unroll
      for (int j = 0; j < 4; ++j)
        storeC(C, (size_t)(row + j) * N + col, acc[m][n][j]);
    }
}

// ---------------- flash attention: split-KV 8-wave, uniform paired blocks ----
// Block = (hk, p): phase 0 runs q-tile 63-p, phase 1 runs q-tile p (uniform
// 16-17 rounds/block). 512 threads = 2 KV-split groups x 4 heads; group g owns
// KV tiles 2i+g with private double-buffered K/V LDS; in-LDS merge per phase.
// Merge pool uses 33-float lane stride (bank = lane, conflict-free).
__global__ __launch_bounds__(512) void attn_kernel(
    const s16* __restrict__ QKV,   // [2048][3072]
    const int* __restrict__ am,    // [2048]
    s16* __restrict__ Ob) {        // [2048][2048]
  // [group][buf]: K at +0 (8KB), V^T at +8192 (8KB); 64KB total.
  __shared__ alignas(16) char smem[65536];
  __shared__ float2 mlb[4][64];

  const int t    = threadIdx.x;
  const int g    = t >> 8;        // kv-split group
  const int tg   = t & 255;       // tid within group
  const int lane = t & 63;
  const int w    = tg >> 6;       // head index within group
  const int col  = lane & 31;     // q column (this wave's q-row index)
  const int hi   = lane >> 5;

  const int hk = blockIdx.x;
  const int p  = blockIdx.y;      // 0..31
  const int h  = hk * 4 + w;
  const int kbase = 2048 + hk * 64;
  const int vbase = 2560 + hk * 64;
  const float CF = 0.18033688f;  // 0.125 * log2(e)

  const int krow   = lane >> 3;
  const int kslotb = lane & 7;
  const int vkv    = 2 * (tg >> 3);
  const int vd8    = (tg & 7) * 8;

  for (int phase = 0; phase < 2; ++phase) {
    const int qt = phase ? p : 63 - p;
    const int nt = (qt >> 1) + 1;
    const int R  = (nt + 1) >> 1;   // rounds (2 tiles per round)
    const int qrow = qt * 32 + col;

    bf16x8 qf[4];
#pragma unroll
    for (int ds = 0; ds < 4; ++ds)
      qf[ds] = *(const bf16x8*)&QKV[(size_t)qrow * QKVW + h * 64 + ds * 16 + hi * 8];

    // ---- prologue: group g stages tile g into its buf 0 ----
    if (g < nt) {
      char* Kn = smem + (g * 2 + 0) * 16384;
      char* Vn = Kn + 8192;
#pragma unroll
      for (int pp = 0; pp < 2; ++pp) {
        int c   = w * 2 + pp;
        int row = c * 8 + krow;
        int slot = kslotb ^ swz7(row);
        gload16(&QKV[(size_t)(g * 64 + row) * QKVW + kbase + slot * 8], Kn + c * 1024);
      }
      bf16x8 va = *(const bf16x8*)&QKV[(size_t)(g * 64 + vkv) * QKVW + vbase + vd8];
      bf16x8 vb = *(const bf16x8*)&QKV[(size_t)(g * 64 + vkv + 1) * QKVW + vbase + vd8];
#pragma unroll
      for (int i = 0; i < 8; ++i) {
        int d = vd8 + i;
        u32 pk = (u32)(u16)va[i] | ((u32)(u16)vb[i] << 16);
        *(u32*)&Vn[(d * 128 + vkv * 2) ^ (swz7(d) << 4)] = pk;
      }
    }
    int acur = am[g * 64 + lane];

    float m_i = -1e30f, l_part = 0.f;
    f32x16 Oacc[2];
#pragma unroll
    for (int b = 0; b < 2; ++b)
#pragma unroll
      for (int i = 0; i < 16; ++i) Oacc[b][i] = 0.f;
    __syncthreads();

    for (int it = 0; it < R; ++it) {
      const int buf  = it & 1;
      const int tile = 2 * it + g;
      const bool valid = (tile < nt);
      const int kv0  = tile * 64;
      const bool pre = (tile + 2 < nt);

      char* Kc = smem + (g * 2 + buf) * 16384;
      char* Vc = Kc + 8192;
      char* Kn = smem + (g * 2 + (buf ^ 1)) * 16384;
      char* Vn = Kn + 8192;

      // ---- async stage of this group's next tile (issue early) ----
      bf16x8 va, vb;
      int anext = 0;
      if (pre) {
        const int nk0 = kv0 + 128;
#pragma unroll
        for (int pp = 0; pp < 2; ++pp) {
          int c   = w * 2 + pp;
          int row = c * 8 + krow;
          int slot = kslotb ^ swz7(row);
          gload16(&QKV[(size_t)(nk0 + row) * QKVW + kbase + slot * 8], Kn + c * 1024);
        }
        va = *(const bf16x8*)&QKV[(size_t)(nk0 + vkv) * QKVW + vbase + vd8];
        vb = *(const bf16x8*)&QKV[(size_t)(nk0 + vkv + 1) * QKVW + vbase + vd8];
        anext = am[nk0 + lane];
      }

      if (valid) {
        // ---- S^T = K Q^T (32x32x16) ----
        f32x16 s0, s1;
#pragma unroll
        for (int i = 0; i < 16; ++i) { s0[i] = 0.f; s1[i] = 0.f; }
        __builtin_amdgcn_s_setprio(1);
#pragma unroll
        for (int ds = 0; ds < 4; ++ds) {
          int off = ds * 32 + hi * 16;
          bf16x8 k0 = *(bf16x8*)&Kc[(col * 128 + off) ^ (swz7(col) << 4)];
          bf16x8 k1 = *(bf16x8*)&Kc[((32 + col) * 128 + off) ^ (swz7(32 + col) << 4)];
          s0 = __builtin_amdgcn_mfma_f32_32x32x16_bf16(k0, qf[ds], s0, 0, 0, 0);
          s1 = __builtin_amdgcn_mfma_f32_32x32x16_bf16(k1, qf[ds], s1, 0, 0, 0);
        }
        __builtin_amdgcn_s_setprio(0);

        // ---- mask (raw domain; CF folded into exp's fma) ----
        float pvv[32];
        unsigned long long m64 = __ballot(acur != 0);
        bool interior = (kv0 + 64 <= qt * 32) && (m64 == ~0ull);
        if (interior) {
#pragma unroll
          for (int r = 0; r < 16; ++r) { pvv[r] = s0[r]; pvv[16 + r] = s1[r]; }
        } else {
#pragma unroll
          for (int b = 0; b < 2; ++b)
#pragma unroll
            for (int r = 0; r < 16; ++r) {
              int kvl = b * 32 + (r & 3) + 8 * (r >> 2) + 4 * hi;
              float sv = b ? s1[r] : s0[r];
              bool ok = (kvl + kv0 <= qrow) && ((m64 >> kvl) & 1ull);
              pvv[b * 16 + r] = ok ? sv : -INFINITY;
            }
        }

        // ---- online softmax (4-way trees + 1 cross-half shfl) ----
        float a0 = pvv[0], a1 = pvv[1], a2 = pvv[2], a3 = pvv[3];
#pragma unroll
        for (int i = 4; i < 32; i += 4) {
          a0 = fmaxf(a0, pvv[i]);     a1 = fmaxf(a1, pvv[i + 1]);
          a2 = fmaxf(a2, pvv[i + 2]); a3 = fmaxf(a3, pvv[i + 3]);
        }
        float lmax = fmaxf(fmaxf(a0, a1), fmaxf(a2, a3));
        lmax = fmaxf(lmax, __shfl_xor(lmax, 32));
        float lmaxs = lmax * CF;

        if (!__all(lmaxs - m_i <= 8.f)) {   // defer-max (T13)
          float nm = fmaxf(m_i, lmaxs);
          float al = __builtin_amdgcn_exp2f(m_i - nm);
          m_i = nm;
          l_part *= al;
#pragma unroll
          for (int b = 0; b < 2; ++b)
#pragma unroll
            for (int i = 0; i < 16; ++i) Oacc[b][i] *= al;
        }

        float t0 = 0.f, t1 = 0.f, t2 = 0.f, t3 = 0.f;
#pragma unroll
        for (int i = 0; i < 32; i += 4) {
          pvv[i]     = __builtin_amdgcn_exp2f(__builtin_fmaf(pvv[i],     CF, -m_i)); t0 += pvv[i];
          pvv[i + 1] = __builtin_amdgcn_exp2f(__builtin_fmaf(pvv[i + 1], CF, -m_i)); t1 += pvv[i + 1];
          pvv[i + 2] = __builtin_amdgcn_exp2f(__builtin_fmaf(pvv[i + 2], CF, -m_i)); t2 += pvv[i + 2];
          pvv[i + 3] = __builtin_amdgcn_exp2f(__builtin_fmaf(pvv[i + 3], CF, -m_i)); t3 += pvv[i + 3];
        }
        l_part += (t0 + t1) + (t2 + t3);

        // ---- P -> PV B-fragments in-register via cvt_pk + permlane32_swap ----
        bf16x8 pf[4];
#pragma unroll
        for (int b = 0; b < 2; ++b)
#pragma unroll
          for (int gg = 0; gg < 2; ++gg) {
            int base = b * 16 + gg * 8;
            u32 A1 = cvtpk(pvv[base + 0], pvv[base + 1]);
            u32 A2 = cvtpk(pvv[base + 2], pvv[base + 3]);
            u32 B1 = cvtpk(pvv[base + 4], pvv[base + 5]);
            u32 B2 = cvtpk(pvv[base + 6], pvv[base + 7]);
            pls(A1, B1);
            pls(A2, B2);
            u32x4 pw; pw[0] = A1; pw[1] = A2; pw[2] = B1; pw[3] = B2;
            pf[b * 2 + gg] = *reinterpret_cast<bf16x8*>(&pw);
          }

        // ---- O^T += V^T P^T ----
        __builtin_amdgcn_s_setprio(1);
#pragma unroll
        for (int ks = 0; ks < 4; ++ks) {
          int off = ks * 32 + hi * 16;
#pragma unroll
          for (int db = 0; db < 2; ++db) {
            int d = db * 32 + col;
            bf16x8 vf = *(bf16x8*)&Vc[(d * 128 + off) ^ (swz7(d) << 4)];
            Oacc[db] = __builtin_amdgcn_mfma_f32_32x32x16_bf16(vf, pf[ks], Oacc[db], 0, 0, 0);
          }
        }
        __builtin_amdgcn_s_setprio(0);
      }

      // ---- late half of async stage: pack + write V^T(next) ----
      if (pre) {
#pragma unroll
        for (int i = 0; i < 8; ++i) {
          int d = vd8 + i;
          u32 pk = (u32)(u16)va[i] | ((u32)(u16)vb[i] << 16);
          *(u32*)&Vn[(d * 128 + vkv * 2) ^ (swz7(d) << 4)] = pk;
        }
        acur = anext;
      }
      __syncthreads();
    }

    // ---- merge the two groups' partials (in LDS), g1 stores final O ----
    // pool stride = 33 floats/lane: bank = (lane*33)%32 = lane, conflict-free.
    float l_p = l_part + __shfl_xor(l_part, 32);

    if (g == 0) {
      // overlays only group 0's own staging area (first 32KB); 4*64*33*4B = 33.8KB <= 32KB?
      // per-wave region: 64 lanes * 33 floats = 8448B; 4 waves = 33792B > 32768.
      // keep waves 0-2 in group-0 area, wave 3 spills into group-1's buf0 K region
      // (already consumed this phase; re-staged next phase after barrier). Safe:
      // next-phase staging happens after the __syncthreads below.
      float* pool = (float*)smem + w * 2176 + lane * 33;
#pragma unroll
      for (int b = 0; b < 2; ++b)
#pragma unroll
        for (int i = 0; i < 16; ++i) pool[b * 16 + i] = Oacc[b][i];
      mlb[w][lane] = make_float2(m_i, l_p);
    }
    __syncthreads();
    if (g == 1) {
      const float* pool = (const float*)smem + w * 2176 + lane * 33;
      float2 ml0 = mlb[w][lane];
      float mm = fmaxf(ml0.x, m_i);
      float b0 = __builtin_amdgcn_exp2f(ml0.x - mm);
      float b1 = __builtin_amdgcn_exp2f(m_i - mm);
      float linv = 1.0f / (ml0.y * b0 + l_p * b1);
      float sc0 = b0 * linv, sc1 = b1 * linv;
#pragma unroll
      for (int db = 0; db < 2; ++db)
#pragma unroll
        for (int qd = 0; qd < 4; ++qd) {
          float o0 = pool[db * 16 + qd * 4 + 0] * sc0 + Oacc[db][qd * 4 + 0] * sc1;
          float o1 = pool[db * 16 + qd * 4 + 1] * sc0 + Oacc[db][qd * 4 + 1] * sc1;
          float o2 = pool[db * 16 + qd * 4 + 2] * sc0 + Oacc[db][qd * 4 + 2] * sc1;
          float o3 = pool[db * 16 + qd * 4 + 3] * sc0 + Oacc[db][qd * 4 + 3] * sc1;
          u32x2 o;
          o[0] = cvtpk(o0, o1);
          o[1] = cvtpk(o2, o3);
          int d0 = db * 32 + qd * 8 + hi * 4;
          *(u32x2*)&Ob[(size_t)qrow * HIDN + h * 64 + d0] = o;
        }
    }
    __syncthreads();  // pool/mlb consumed before next phase's staging
  }
}

extern "C" void kernel_launch(void* const* d_in, const int* in_sizes, int n_in,
                              void* d_out, int out_size, void* d_ws, size_t ws_size,
                              hipStream_t stream) {
  const float* hidden = (const float*)d_in[0];
  const int*   am     = (const int*)d_in[1];
  const float* Wq     = (const float*)d_in[2];
  const float* Wk     = (const float*)d_in[3];
  const float* Wv     = (const float*)d_in[4];
  const float* Wo     = (const float*)d_in[5];
  float* out = (float*)d_out;

  s16* hb    = (s16*)d_ws;          // hidden  [2048][2048]
  s16* wqkvb = hb    + 4194304;     // W_qkv   [3072][2048]
  s16* wob   = wqkvb + 6291456;     // Wo      [2048][2048]
  s16* QKVb  = wob   + 4194304;     // QKV     [2048][3072]
  s16* Ab    = QKVb  + 6291456;     // attnout [2048][2048]

  cvt_all<<<14336, 256, 0, stream>>>(hidden, Wq, Wk, Wv, Wo, (s16x4*)d_ws);

  gemm_bt<s16><<<384, 512, 0, stream>>>(hb, wqkvb, QKVb, 2048, 3072, 2048, 24);

  attn_kernel<<<dim3(8, 32), 512, 0, stream>>>(QKVb, am, Ab);

  gemm_bt<float><<<256, 512, 0, stream>>>(Ab, wob, out, 2048, 2048, 2048, 16);
}